// Round 4
// baseline (8363.315 us; speedup 1.0000x reference)
//
#include <hip/hip_runtime.h>
#include <hip/hip_bf16.h>

typedef __attribute__((ext_vector_type(4))) float f32x4;
typedef __attribute__((ext_vector_type(8))) short s16x8;

#define DEVFN static __device__ __forceinline__

// ---- problem sizes ----
#define TT  160
#define BB  640
#define DD  40
#define HH  768
#define PP  256
#define G4H 3072

// ---- geometry (round-0 proven config) ----
#define NGATE 144      // 3 layers * 2 bc * 24 hg
#define NPROJ 48       // 3 layers * 4 mt * 4 nt
#define NWG   192
#define NTHR  256
#define SSTEPS 164     // 160 + 2*2 pipeline skew

#define KH  256
#define KX0 64         // layer0 x-K padded 40 -> 64

// LDS strides (elements), +8 pad keeps 16B alignment and breaks worst conflicts
#define STW1 328       // layer0: 320+8
#define STW2 520       // layer1/2: 512+8
#define STP  776       // proj: 768+8
#define LDS_ELEMS 66560  // 128*520 = 133,120 bytes

// ---- workspace layout ----
#define XP_BYTES   (TT*BB*64*2)
#define HR_BYTES   (3*4*BB*PP*2)
#define SB_BYTES   (3*BB*HH*2)
#define XP_OFF     0
#define HR_OFF     (XP_OFF + XP_BYTES)
#define SB_OFF     (HR_OFF + HR_BYTES)
#define SYNC_OFF   (SB_OFF + SB_BYTES)
#define SYNC_BYTES 4096

DEVFN float sigm(float v)  { return __fdividef(1.f, 1.f + __expf(-v)); }
DEVFN float tanh_(float v) { return 2.f * __fdividef(1.f, 1.f + __expf(-2.f * v)) - 1.f; }
DEVFN f32x4 f4zero() { f32x4 v; v[0]=0.f; v[1]=0.f; v[2]=0.f; v[3]=0.f; return v; }

// write-through bf16 store: visible at coherence point once vmcnt retires,
// no L2 writeback fence needed on the release side.
DEVFN void gst_b16(__hip_bfloat16* p, __hip_bfloat16 v) {
  unsigned short u = __builtin_bit_cast(unsigned short, v);
  asm volatile("global_store_short %0, %1, off sc0 sc1" :: "v"(p), "v"(u));
}

// cache-bypassing 4B load/store (coherence-point access, fresh values)
DEVFN unsigned ld_cc(const unsigned* p) {
  unsigned v;
  asm volatile("global_load_dword %0, %1, off sc0 sc1\n\ts_waitcnt vmcnt(0)"
               : "=v"(v) : "v"(p) : "memory");
  return v;
}
DEVFN void st_cc(unsigned* p, unsigned v) {
  asm volatile("global_store_dword %0, %1, off sc0 sc1" :: "v"(p), "v"(v) : "memory");
}
DEVFN void ld3_cc(const unsigned* p0, const unsigned* p1, const unsigned* p2,
                  unsigned& a, unsigned& b, unsigned& c) {
  asm volatile("global_load_dword %0, %3, off sc0 sc1\n\t"
               "global_load_dword %1, %4, off sc0 sc1\n\t"
               "global_load_dword %2, %5, off sc0 sc1\n\t"
               "s_waitcnt vmcnt(0)"
               : "=&v"(a), "=&v"(b), "=&v"(c)
               : "v"(p0), "v"(p1), "v"(p2) : "memory");
}

// ---- flag-array grid barrier: ZERO atomic contention.
// sync[0] = epoch; sync[64+i] = arrival flag of block i. Master = block 0
// wave 0 polls all 192 flags with 3 batched bypass-loads, publishes epoch.
DEVFN void gridbar(unsigned* sync, int bid, int tid, unsigned k) {
  __syncthreads();   // compiler drains vmcnt(0): all sc0sc1 stores at coherence point
  if (tid == 0) st_cc(sync + 64 + bid, k);
  if (bid == 0 && tid < 64) {
    unsigned a, b, c;
    for (;;) {
      ld3_cc(sync + 64 + tid, sync + 128 + tid, sync + 192 + tid, a, b, c);
      if (__all((a >= k) & (b >= k) & (c >= k))) break;
      __builtin_amdgcn_s_sleep(1);
    }
    if (tid == 0) st_cc(sync, k);
  }
  if (tid == 0) {
    while (ld_cc(sync) < k) __builtin_amdgcn_s_sleep(1);
    __builtin_amdgcn_fence(__ATOMIC_ACQUIRE, "agent");  // buffer_inv: kill stale L1/L2 lines
  }
  __syncthreads();
}

__global__ __launch_bounds__(NTHR, 1)
void lstmp_persistent(const float* __restrict__ xin,
                      const float* __restrict__ W0, const float* __restrict__ b0, const float* __restrict__ Wp0,
                      const float* __restrict__ W1, const float* __restrict__ b1, const float* __restrict__ Wp1,
                      const float* __restrict__ W2, const float* __restrict__ b2, const float* __restrict__ Wp2,
                      float* __restrict__ outp, unsigned char* __restrict__ ws)
{
  __shared__ __align__(16) __hip_bfloat16 lds[LDS_ELEMS];

  const int bid  = blockIdx.x;
  const int tid  = threadIdx.x;
  const int lane = tid & 63;
  const int wave = tid >> 6;
  const int q    = lane >> 4;     // 0..3
  const int c16  = lane & 15;

  __hip_bfloat16* Xp = (__hip_bfloat16*)(ws + XP_OFF);  // [160][640][64] bf16, cols>=40 zero
  __hip_bfloat16* Hr = (__hip_bfloat16*)(ws + HR_OFF);  // [3][4 ring][640][256] bf16
  __hip_bfloat16* Sb = (__hip_bfloat16*)(ws + SB_OFF);  // [3][640][768] bf16
  unsigned* sync     = (unsigned*)(ws + SYNC_OFF);

  // ---- XCD-aware role decode: bid%8 == XCD (round-robin dispatch, 24 blocks/XCD).
  const int xcd  = bid & 7;
  const int slot = bid >> 3;      // 0..23
  const bool isGate = (xcd < 6);
  int l = 0, bc = 0, hg = 0, mt = 0, nt = 0;
  if (isGate) { l = xcd >> 1; bc = xcd & 1; hg = slot; }
  else        { l = slot >> 3; int r = slot & 7; mt = (xcd - 6) * 2 + (r >> 2); nt = r & 3; }

  const int KX  = (l == 0) ? KX0 : 256;
  const int KT  = KX + KH;                  // 320 or 512
  const int STW = (l == 0) ? STW1 : STW2;

  const float* Wl  = (l == 0) ? W0  : ((l == 1) ? W1  : W2);
  const float* bl  = (l == 0) ? b0  : ((l == 1) ? b1  : b2);
  const float* Wpl = (l == 0) ? Wp0 : ((l == 1) ? Wp1 : Wp2);

  // ---------- pre-phase: pack x -> Xp (all blocks share the work) ----------
  for (int e = bid * NTHR + tid; e < TT * BB * 64; e += NWG * NTHR) {
    int k  = e & 63;
    int tb = e >> 6;
    float v = (k < DD) ? xin[(size_t)tb * DD + k] : 0.f;
    gst_b16(&Xp[e], __float2bfloat16(v));
  }

  // ---------- pre-phase: pack weights (transposed) into this block's LDS ----------
  if (isGate) {
    for (int idx = tid; idx < 128 * KT; idx += NTHR) {
      int kk = idx >> 7;
      int nn = idx & 127;
      int col = (nn >> 5) * HH + hg * 32 + (nn & 31);
      float v;
      if (l == 0) {
        v = (kk < DD) ? Wl[(size_t)kk * G4H + col]
                      : ((kk < KX0) ? 0.f : Wl[(size_t)(kk - 24) * G4H + col]);
      } else {
        v = Wl[(size_t)kk * G4H + col];
      }
      lds[nn * STW + kk] = __float2bfloat16(v);
    }
  } else {
    for (int idx = tid; idx < 64 * HH; idx += NTHR) {
      int kk = idx >> 6;
      int nn = idx & 63;
      lds[nn * STP + kk] = __float2bfloat16(Wpl[(size_t)kk * PP + nt * 64 + nn]);
    }
  }

  // ---------- per-lane gate setup ----------
  const int wmg = wave >> 1, wng = wave & 1;
  const int m0g = bc * 320 + wmg * 160;      // this wave's batch-row base (gate)
  const int hcl = wng * 16 + c16;            // 0..31 within WG's 32 h-cols
  float biasv[4] = {0.f, 0.f, 0.f, 0.f};
  if (isGate) {
#pragma unroll
    for (int g = 0; g < 4; ++g) biasv[g] = bl[g * HH + hg * 32 + hcl];
  }

  f32x4 acc[10][4];    // z-tile accumulator: 10 m-frags x 4 gates
  float cst[10][4];    // c-state: 10 m-frags x 4 rows
#pragma unroll
  for (int mi = 0; mi < 10; ++mi) {
#pragma unroll
    for (int g = 0; g < 4; ++g) { acc[mi][g] = f4zero(); cst[mi][g] = 0.f; }
  }

  // gate GEMM: acc += A[m0g:+160, 0:klen] @ Wt[kbase:kbase+klen, :]
  auto gate_gemm = [&](const __hip_bfloat16* A, int lda, int kbase, int klen) {
    for (int ks = 0; ks < klen; ks += 32) {
      s16x8 av[10];
#pragma unroll
      for (int mi = 0; mi < 10; ++mi)
        av[mi] = *(const s16x8*)(A + (size_t)(m0g + mi * 16 + c16) * lda + ks + 8 * q);
      s16x8 bv[4];
#pragma unroll
      for (int g = 0; g < 4; ++g)
        bv[g] = *(const s16x8*)(lds + (g * 32 + hcl) * STW + kbase + ks + 8 * q);
#pragma unroll
      for (int mi = 0; mi < 10; ++mi) {
#pragma unroll
        for (int g = 0; g < 4; ++g)
          acc[mi][g] = __builtin_amdgcn_mfma_f32_16x16x32_bf16(av[mi], bv[g], acc[mi][g], 0, 0, 0);
      }
    }
  };

  // c-update + s = sig(o)*tanh(c) -> Sbuf; zeroes acc for the next x-shadow
  auto gate_update = [&]() {
    __hip_bfloat16* S = Sb + (size_t)l * BB * HH;
#pragma unroll
    for (int mi = 0; mi < 10; ++mi) {
#pragma unroll
      for (int r = 0; r < 4; ++r) {
        float iv = acc[mi][0][r] + biasv[0];
        float jv = acc[mi][1][r] + biasv[1];
        float fv = acc[mi][2][r] + biasv[2];
        float ov = acc[mi][3][r] + biasv[3];
        float c  = sigm(fv + 1.f) * cst[mi][r] + sigm(iv) * tanh_(jv);
        cst[mi][r] = c;
        float sv = sigm(ov) * tanh_(c);
        gst_b16(&S[(size_t)(m0g + mi * 16 + q * 4 + r) * HH + hg * 32 + hcl],
                __float2bfloat16(sv));
      }
#pragma unroll
      for (int g = 0; g < 4; ++g) acc[mi][g] = f4zero();
    }
  };

  // proj: h_t[tile] = Sb[l] @ Wp_slice -> Hr ring slot (t+1)&3
  // 4-deep software-pipelined: 20 A-loads in flight hide the post-inv L3 miss
  // latency (~1000 cyc) that the 24-iteration serial chain otherwise exposes.
  auto proj_do = [&](int t) {
    const __hip_bfloat16* A = Sb + (size_t)l * BB * HH;
    const int m0p = mt * 160 + (wave >> 1) * 80;
    const int np0 = (wave & 1) * 32;
    const __hip_bfloat16* ab[5];
#pragma unroll
    for (int mi = 0; mi < 5; ++mi)
      ab[mi] = A + (size_t)(m0p + mi * 16 + c16) * HH + 8 * q;
    f32x4 pa[5][2];
#pragma unroll
    for (int mi = 0; mi < 5; ++mi) { pa[mi][0] = f4zero(); pa[mi][1] = f4zero(); }
    s16x8 avp[4][5];                 // 4-stage prefetch ring (80 VGPR)
#pragma unroll
    for (int pf = 0; pf < 4; ++pf)
#pragma unroll
      for (int mi = 0; mi < 5; ++mi)
        avp[pf][mi] = *(const s16x8*)(ab[mi] + pf * 32);
#pragma unroll
    for (int it = 0; it < 24; ++it) {        // fully unrolled: all indices static
      const int ks = it * 32;
      s16x8 bv[2];
#pragma unroll
      for (int ni = 0; ni < 2; ++ni)
        bv[ni] = *(const s16x8*)(lds + (np0 + ni * 16 + c16) * STP + ks + 8 * q);
      s16x8 cur[5];
#pragma unroll
      for (int mi = 0; mi < 5; ++mi) cur[mi] = avp[it & 3][mi];
      if (it + 4 < 24) {
#pragma unroll
        for (int mi = 0; mi < 5; ++mi)
          avp[it & 3][mi] = *(const s16x8*)(ab[mi] + (it + 4) * 32);
      }
#pragma unroll
      for (int mi = 0; mi < 5; ++mi) {
#pragma unroll
        for (int ni = 0; ni < 2; ++ni)
          pa[mi][ni] = __builtin_amdgcn_mfma_f32_16x16x32_bf16(cur[mi], bv[ni], pa[mi][ni], 0, 0, 0);
      }
    }
    __hip_bfloat16* Hd = Hr + ((size_t)l * 4 + ((unsigned)(t + 1) & 3)) * BB * PP;
#pragma unroll
    for (int mi = 0; mi < 5; ++mi)
#pragma unroll
      for (int ni = 0; ni < 2; ++ni)
#pragma unroll
        for (int r = 0; r < 4; ++r)
          gst_b16(&Hd[(size_t)(m0p + mi * 16 + q * 4 + r) * PP + nt * 64 + np0 + ni * 16 + c16],
                  __float2bfloat16(pa[mi][ni][r]));
  };

  // ---------- main pipelined scan ----------
  unsigned bark = 1;
  gridbar(sync, bid, tid, bark++);          // packs done (Xp + LDS)

  if (isGate && l == 0) gate_gemm(Xp, 64, 0, KX0);   // zx(0) for layer 0

  for (int s = 0; s < SSTEPS; ++s) {
    const int t = s - 2 * l;           // this layer's timestep
    // phase 1: gates (acc already holds zx(t)) + c-update + s-write
    if (isGate && t >= 0 && t < TT) {
      gate_gemm(Hr + ((size_t)l * 4 + ((unsigned)t & 3)) * BB * PP, PP, KX, KH);  // h_{t-1} part
      gate_update();
    }
    gridbar(sync, bid, tid, bark++);
    // phase 2: proj(t)  ||  gate x-shadow: zx(t+1)
    if (isGate) {
      const int tp = t + 1;
      if (tp >= 0 && tp < TT) {
        if (l == 0) gate_gemm(Xp + (size_t)tp * BB * 64, 64, 0, KX0);
        else        gate_gemm(Hr + ((size_t)(l - 1) * 4 + ((unsigned)(tp + 1) & 3)) * BB * PP, PP, 0, 256);
      }
    } else if (t >= 0 && t < TT) {
      proj_do(t);
    }
    gridbar(sync, bid, tid, bark++);
  }

  // ---------- epilogue: L2-normalize h^2[159] (ring slot 0) ----------
  const __hip_bfloat16* hf = Hr + (size_t)(2 * 4 + 0) * BB * PP;
  float* red = reinterpret_cast<float*>(lds);   // weights dead now, reuse LDS
  for (int row = bid; row < BB; row += NWG) {
    float v = __bfloat162float(hf[(size_t)row * PP + tid]);
    float ssq = v * v;
#pragma unroll
    for (int off = 32; off > 0; off >>= 1) ssq += __shfl_down(ssq, off, 64);
    if (lane == 0) red[wave] = ssq;
    __syncthreads();
    float tot = red[0] + red[1] + red[2] + red[3];
    outp[(size_t)row * PP + tid] = v * __fdividef(1.f, sqrtf(tot) + 1e-6f);
    __syncthreads();
  }
}

extern "C" void kernel_launch(void* const* d_in, const int* in_sizes, int n_in,
                              void* d_out, int out_size, void* d_ws, size_t ws_size,
                              hipStream_t stream) {
  (void)in_sizes; (void)n_in; (void)out_size; (void)ws_size;
  unsigned char* ws = (unsigned char*)d_ws;
  // zero h-ring (h_{-1} = 0) and barrier flags every call (replay-safe)
  hipMemsetAsync(ws + HR_OFF, 0, HR_BYTES, stream);
  hipMemsetAsync(ws + SYNC_OFF, 0, SYNC_BYTES, stream);
  lstmp_persistent<<<dim3(NWG), dim3(NTHR), 0, stream>>>(
      (const float*)d_in[0],
      (const float*)d_in[1], (const float*)d_in[2], (const float*)d_in[3],
      (const float*)d_in[4], (const float*)d_in[5], (const float*)d_in[6],
      (const float*)d_in[7], (const float*)d_in[8], (const float*)d_in[9],
      (float*)d_out, ws);
}

// Round 5
// 6944.337 us; speedup vs baseline: 1.2043x; 1.2043x over previous
//
#include <hip/hip_runtime.h>
#include <hip/hip_bf16.h>

typedef __attribute__((ext_vector_type(4))) float f32x4;
typedef __attribute__((ext_vector_type(8))) short s16x8;

#define DEVFN static __device__ __forceinline__

// ---- problem sizes ----
#define TT  160
#define BB  640
#define DD  40
#define HH  768
#define PP  256
#define G4H 3072

// ---- geometry (round-0 proven config) ----
#define NGATE 144      // 3 layers * 2 bc * 24 hg
#define NPROJ 48       // 3 layers * 4 mt * 4 nt
#define NWG   192
#define NTHR  256
#define SSTEPS 164     // 160 + 2*2 pipeline skew

#define KH  256
#define KX0 64         // layer0 x-K padded 40 -> 64

// LDS strides (elements), +8 pad keeps 16B alignment and breaks worst conflicts
#define STW1 328       // layer0: 320+8
#define STW2 520       // layer1/2: 512+8
#define STP  776       // proj: 768+8
#define LDS_ELEMS 66560  // 128*520 = 133,120 bytes

// ---- workspace layout ----
#define XP_BYTES   (TT*BB*64*2)
#define HR_BYTES   (3*4*BB*PP*2)
#define SB_BYTES   (3*BB*HH*2)
#define XP_OFF     0
#define HR_OFF     (XP_OFF + XP_BYTES)
#define SB_OFF     (HR_OFF + HR_BYTES)
#define SYNC_OFF   (SB_OFF + SB_BYTES)
#define SYNC_BYTES 4096

DEVFN float sigm(float v)  { return __fdividef(1.f, 1.f + __expf(-v)); }
DEVFN float tanh_(float v) { return 2.f * __fdividef(1.f, 1.f + __expf(-2.f * v)) - 1.f; }
DEVFN f32x4 f4zero() { f32x4 v; v[0]=0.f; v[1]=0.f; v[2]=0.f; v[3]=0.f; return v; }

// write-through bf16 store: visible at coherence point once vmcnt retires,
// no L2 writeback fence needed on the release side.
DEVFN void gst_b16(__hip_bfloat16* p, __hip_bfloat16 v) {
  unsigned short u = __builtin_bit_cast(unsigned short, v);
  asm volatile("global_store_short %0, %1, off sc0 sc1" :: "v"(p), "v"(u));
}

// cache-bypassing 4B load/store (coherence-point access, fresh values)
DEVFN unsigned ld_cc(const unsigned* p) {
  unsigned v;
  asm volatile("global_load_dword %0, %1, off sc0 sc1\n\ts_waitcnt vmcnt(0)"
               : "=v"(v) : "v"(p) : "memory");
  return v;
}
DEVFN void st_cc(unsigned* p, unsigned v) {
  asm volatile("global_store_dword %0, %1, off sc0 sc1" :: "v"(p), "v"(v) : "memory");
}
DEVFN void ld3_cc(const unsigned* p0, const unsigned* p1, const unsigned* p2,
                  unsigned& a, unsigned& b, unsigned& c) {
  asm volatile("global_load_dword %0, %3, off sc0 sc1\n\t"
               "global_load_dword %1, %4, off sc0 sc1\n\t"
               "global_load_dword %2, %5, off sc0 sc1\n\t"
               "s_waitcnt vmcnt(0)"
               : "=&v"(a), "=&v"(b), "=&v"(c)
               : "v"(p0), "v"(p1), "v"(p2) : "memory");
}

// ---- flag-array grid barrier: ZERO atomic contention.
// sync[0] = epoch; sync[64+i] = arrival flag of block i. Master = block 0
// wave 0 polls all 192 flags with 3 batched bypass-loads, publishes epoch.
DEVFN void gridbar(unsigned* sync, int bid, int tid, unsigned k) {
  __syncthreads();   // compiler drains vmcnt(0): all sc0sc1 stores at coherence point
  if (tid == 0) st_cc(sync + 64 + bid, k);
  if (bid == 0 && tid < 64) {
    unsigned a, b, c;
    for (;;) {
      ld3_cc(sync + 64 + tid, sync + 128 + tid, sync + 192 + tid, a, b, c);
      if (__all((a >= k) & (b >= k) & (c >= k))) break;
      __builtin_amdgcn_s_sleep(1);
    }
    if (tid == 0) st_cc(sync, k);
  }
  if (tid == 0) {
    while (ld_cc(sync) < k) __builtin_amdgcn_s_sleep(1);
    __builtin_amdgcn_fence(__ATOMIC_ACQUIRE, "agent");  // buffer_inv: kill stale L1/L2 lines
  }
  __syncthreads();
}

__global__ __launch_bounds__(NTHR, 1)
void lstmp_persistent(const float* __restrict__ xin,
                      const float* __restrict__ W0, const float* __restrict__ b0, const float* __restrict__ Wp0,
                      const float* __restrict__ W1, const float* __restrict__ b1, const float* __restrict__ Wp1,
                      const float* __restrict__ W2, const float* __restrict__ b2, const float* __restrict__ Wp2,
                      float* __restrict__ outp, unsigned char* __restrict__ ws)
{
  __shared__ __align__(16) __hip_bfloat16 lds[LDS_ELEMS];

  const int bid  = blockIdx.x;
  const int tid  = threadIdx.x;
  const int lane = tid & 63;
  const int wave = tid >> 6;
  const int q    = lane >> 4;     // 0..3
  const int c16  = lane & 15;

  __hip_bfloat16* Xp = (__hip_bfloat16*)(ws + XP_OFF);  // [160][640][64] bf16, cols>=40 zero
  __hip_bfloat16* Hr = (__hip_bfloat16*)(ws + HR_OFF);  // [3][4 ring][640][256] bf16
  __hip_bfloat16* Sb = (__hip_bfloat16*)(ws + SB_OFF);  // [3][640][768] bf16
  unsigned* sync     = (unsigned*)(ws + SYNC_OFF);

  // ---- XCD-aware role decode: bid%8 == XCD (round-robin dispatch, 24 blocks/XCD).
  const int xcd  = bid & 7;
  const int slot = bid >> 3;      // 0..23
  const bool isGate = (xcd < 6);
  int l = 0, bc = 0, hg = 0, mt = 0, nt = 0;
  if (isGate) { l = xcd >> 1; bc = xcd & 1; hg = slot; }
  else        { l = slot >> 3; int r = slot & 7; mt = (xcd - 6) * 2 + (r >> 2); nt = r & 3; }

  const int KX  = (l == 0) ? KX0 : 256;
  const int KT  = KX + KH;                  // 320 or 512
  const int STW = (l == 0) ? STW1 : STW2;

  const float* Wl  = (l == 0) ? W0  : ((l == 1) ? W1  : W2);
  const float* bl  = (l == 0) ? b0  : ((l == 1) ? b1  : b2);
  const float* Wpl = (l == 0) ? Wp0 : ((l == 1) ? Wp1 : Wp2);

  // ---------- pre-phase: pack x -> Xp (all blocks share the work) ----------
  for (int e = bid * NTHR + tid; e < TT * BB * 64; e += NWG * NTHR) {
    int k  = e & 63;
    int tb = e >> 6;
    float v = (k < DD) ? xin[(size_t)tb * DD + k] : 0.f;
    gst_b16(&Xp[e], __float2bfloat16(v));
  }

  // ---------- pre-phase: pack weights (transposed) into this block's LDS ----------
  if (isGate) {
    for (int idx = tid; idx < 128 * KT; idx += NTHR) {
      int kk = idx >> 7;
      int nn = idx & 127;
      int col = (nn >> 5) * HH + hg * 32 + (nn & 31);
      float v;
      if (l == 0) {
        v = (kk < DD) ? Wl[(size_t)kk * G4H + col]
                      : ((kk < KX0) ? 0.f : Wl[(size_t)(kk - 24) * G4H + col]);
      } else {
        v = Wl[(size_t)kk * G4H + col];
      }
      lds[nn * STW + kk] = __float2bfloat16(v);
    }
  } else {
    for (int idx = tid; idx < 64 * HH; idx += NTHR) {
      int kk = idx >> 6;
      int nn = idx & 63;
      lds[nn * STP + kk] = __float2bfloat16(Wpl[(size_t)kk * PP + nt * 64 + nn]);
    }
  }

  // ---------- main pipelined scan (role-split so proj path carries no gate state) ----------
  unsigned bark = 1;
  gridbar(sync, bid, tid, bark++);          // packs done (Xp + LDS)

  if (isGate) {
    // ----- GATE PATH: acc/cst/biasv live ONLY here (proj path stays lean) -----
    const int wmg = wave >> 1, wng = wave & 1;
    const int m0g = bc * 320 + wmg * 160;      // this wave's batch-row base
    const int hcl = wng * 16 + c16;            // 0..31 within WG's 32 h-cols
    float biasv[4];
#pragma unroll
    for (int g = 0; g < 4; ++g) biasv[g] = bl[g * HH + hg * 32 + hcl];

    f32x4 acc[10][4];    // z-tile accumulator: 10 m-frags x 4 gates
    float cst[10][4];    // c-state
#pragma unroll
    for (int mi = 0; mi < 10; ++mi)
#pragma unroll
      for (int g = 0; g < 4; ++g) { acc[mi][g] = f4zero(); cst[mi][g] = 0.f; }

    auto gate_gemm = [&](const __hip_bfloat16* A, int lda, int kbase, int klen) {
      for (int ks = 0; ks < klen; ks += 32) {
        s16x8 av[10];
#pragma unroll
        for (int mi = 0; mi < 10; ++mi)
          av[mi] = *(const s16x8*)(A + (size_t)(m0g + mi * 16 + c16) * lda + ks + 8 * q);
        s16x8 bv[4];
#pragma unroll
        for (int g = 0; g < 4; ++g)
          bv[g] = *(const s16x8*)(lds + (g * 32 + hcl) * STW + kbase + ks + 8 * q);
#pragma unroll
        for (int mi = 0; mi < 10; ++mi)
#pragma unroll
          for (int g = 0; g < 4; ++g)
            acc[mi][g] = __builtin_amdgcn_mfma_f32_16x16x32_bf16(av[mi], bv[g], acc[mi][g], 0, 0, 0);
      }
    };

    auto gate_update = [&]() {
      __hip_bfloat16* S = Sb + (size_t)l * BB * HH;
#pragma unroll
      for (int mi = 0; mi < 10; ++mi) {
#pragma unroll
        for (int r = 0; r < 4; ++r) {
          float iv = acc[mi][0][r] + biasv[0];
          float jv = acc[mi][1][r] + biasv[1];
          float fv = acc[mi][2][r] + biasv[2];
          float ov = acc[mi][3][r] + biasv[3];
          float c  = sigm(fv + 1.f) * cst[mi][r] + sigm(iv) * tanh_(jv);
          cst[mi][r] = c;
          float sv = sigm(ov) * tanh_(c);
          gst_b16(&S[(size_t)(m0g + mi * 16 + q * 4 + r) * HH + hg * 32 + hcl],
                  __float2bfloat16(sv));
        }
#pragma unroll
        for (int g = 0; g < 4; ++g) acc[mi][g] = f4zero();
      }
    };

    if (l == 0) gate_gemm(Xp, 64, 0, KX0);   // zx(0) for layer 0

    for (int s = 0; s < SSTEPS; ++s) {
      const int t = s - 2 * l;
      if (t >= 0 && t < TT) {
        gate_gemm(Hr + ((size_t)l * 4 + ((unsigned)t & 3)) * BB * PP, PP, KX, KH);
        gate_update();
      }
      gridbar(sync, bid, tid, bark++);
      const int tp = t + 1;
      if (tp >= 0 && tp < TT) {
        if (l == 0) gate_gemm(Xp + (size_t)tp * BB * 64, 64, 0, KX0);
        else        gate_gemm(Hr + ((size_t)(l - 1) * 4 + ((unsigned)(tp + 1) & 3)) * BB * PP, PP, 0, 256);
      }
      gridbar(sync, bid, tid, bark++);
    }
  } else {
    // ----- PROJ PATH: lean registers -> 2-deep ping-pong K-loop pipelining -----
    const int m0p = mt * 160 + (wave >> 1) * 80;
    const int np0 = (wave & 1) * 32;

    for (int s = 0; s < SSTEPS; ++s) {
      gridbar(sync, bid, tid, bark++);       // end of phase 1 (no work here)
      const int t = s - 2 * l;
      if (t >= 0 && t < TT) {
        const __hip_bfloat16* A = Sb + (size_t)l * BB * HH;
        const __hip_bfloat16* ab[5];
#pragma unroll
        for (int mi = 0; mi < 5; ++mi)
          ab[mi] = A + (size_t)(m0p + mi * 16 + c16) * HH + 8 * q;

        f32x4 pa[5][2];
#pragma unroll
        for (int mi = 0; mi < 5; ++mi) { pa[mi][0] = f4zero(); pa[mi][1] = f4zero(); }

        s16x8 a0[5], a1[5];                   // ping-pong prefetch (2 x 20 VGPR)
#pragma unroll
        for (int mi = 0; mi < 5; ++mi) a0[mi] = *(const s16x8*)(ab[mi] + 0);

#pragma unroll 1
        for (int it2 = 0; it2 < 12; ++it2) {  // 2 k-slices per iteration
          const int ks0 = it2 * 64, ks1 = ks0 + 32;
          // prefetch odd half while even half computes
#pragma unroll
          for (int mi = 0; mi < 5; ++mi) a1[mi] = *(const s16x8*)(ab[mi] + ks1);
          s16x8 bv[2];
#pragma unroll
          for (int ni = 0; ni < 2; ++ni)
            bv[ni] = *(const s16x8*)(lds + (np0 + ni * 16 + c16) * STP + ks0 + 8 * q);
#pragma unroll
          for (int mi = 0; mi < 5; ++mi)
#pragma unroll
            for (int ni = 0; ni < 2; ++ni)
              pa[mi][ni] = __builtin_amdgcn_mfma_f32_16x16x32_bf16(a0[mi], bv[ni], pa[mi][ni], 0, 0, 0);
          // prefetch next even half while odd half computes
          if (it2 < 11) {
#pragma unroll
            for (int mi = 0; mi < 5; ++mi) a0[mi] = *(const s16x8*)(ab[mi] + ks0 + 64);
          }
#pragma unroll
          for (int ni = 0; ni < 2; ++ni)
            bv[ni] = *(const s16x8*)(lds + (np0 + ni * 16 + c16) * STP + ks1 + 8 * q);
#pragma unroll
          for (int mi = 0; mi < 5; ++mi)
#pragma unroll
            for (int ni = 0; ni < 2; ++ni)
              pa[mi][ni] = __builtin_amdgcn_mfma_f32_16x16x32_bf16(a1[mi], bv[ni], pa[mi][ni], 0, 0, 0);
        }

        __hip_bfloat16* Hd = Hr + ((size_t)l * 4 + ((unsigned)(t + 1) & 3)) * BB * PP;
#pragma unroll
        for (int mi = 0; mi < 5; ++mi)
#pragma unroll
          for (int ni = 0; ni < 2; ++ni)
#pragma unroll
            for (int r = 0; r < 4; ++r)
              gst_b16(&Hd[(size_t)(m0p + mi * 16 + q * 4 + r) * PP + nt * 64 + np0 + ni * 16 + c16],
                      __float2bfloat16(pa[mi][ni][r]));
      }
      gridbar(sync, bid, tid, bark++);
    }
  }

  // ---------- epilogue: L2-normalize h^2[159] (ring slot 0) ----------
  const __hip_bfloat16* hf = Hr + (size_t)(2 * 4 + 0) * BB * PP;
  float* red = reinterpret_cast<float*>(lds);   // weights dead now, reuse LDS
  for (int row = bid; row < BB; row += NWG) {
    float v = __bfloat162float(hf[(size_t)row * PP + tid]);
    float ssq = v * v;
#pragma unroll
    for (int off = 32; off > 0; off >>= 1) ssq += __shfl_down(ssq, off, 64);
    if (lane == 0) red[wave] = ssq;
    __syncthreads();
    float tot = red[0] + red[1] + red[2] + red[3];
    outp[(size_t)row * PP + tid] = v * __fdividef(1.f, sqrtf(tot) + 1e-6f);
    __syncthreads();
  }
}

extern "C" void kernel_launch(void* const* d_in, const int* in_sizes, int n_in,
                              void* d_out, int out_size, void* d_ws, size_t ws_size,
                              hipStream_t stream) {
  (void)in_sizes; (void)n_in; (void)out_size; (void)ws_size;
  unsigned char* ws = (unsigned char*)d_ws;
  // zero h-ring (h_{-1} = 0) and barrier flags every call (replay-safe)
  hipMemsetAsync(ws + HR_OFF, 0, HR_BYTES, stream);
  hipMemsetAsync(ws + SYNC_OFF, 0, SYNC_BYTES, stream);
  lstmp_persistent<<<dim3(NWG), dim3(NTHR), 0, stream>>>(
      (const float*)d_in[0],
      (const float*)d_in[1], (const float*)d_in[2], (const float*)d_in[3],
      (const float*)d_in[4], (const float*)d_in[5], (const float*)d_in[6],
      (const float*)d_in[7], (const float*)d_in[8], (const float*)d_in[9],
      (float*)d_out, ws);
}

// Round 6
// 6196.216 us; speedup vs baseline: 1.3497x; 1.1207x over previous
//
#include <hip/hip_runtime.h>
#include <hip/hip_bf16.h>

typedef __attribute__((ext_vector_type(4))) float f32x4;
typedef __attribute__((ext_vector_type(8))) short s16x8;

#define DEVFN static __device__ __forceinline__

// ---- problem sizes ----
#define TT  160
#define BB  640
#define DD  40
#define HH  768
#define PP  256
#define G4H 3072

// ---- geometry (round-0 proven config) ----
#define NWG   192
#define NTHR  256

#define KH  256
#define KX0 64         // layer0 x-K padded 40 -> 64

// LDS strides (elements), +8 pad keeps 16B alignment and breaks worst conflicts
#define STW1 328       // layer0: 320+8
#define STW2 520       // layer1/2: 512+8
#define STP  776       // proj: 768+8
#define LDS_ELEMS 66560  // 128*520 = 133,120 bytes

// ---- workspace layout ----
#define XP_BYTES   (TT*BB*64*2)
#define HR_BYTES   (3*4*BB*PP*2)
#define SB_BYTES   (3*BB*HH*2)
#define XP_OFF     0
#define HR_OFF     (XP_OFF + XP_BYTES)
#define SB_OFF     (HR_OFF + HR_BYTES)
#define SYNC_OFF   (SB_OFF + SB_BYTES)
#define SYNC_BYTES 4096

DEVFN float sigm(float v)  { return __fdividef(1.f, 1.f + __expf(-v)); }
DEVFN float tanh_(float v) { return 2.f * __fdividef(1.f, 1.f + __expf(-2.f * v)) - 1.f; }
DEVFN f32x4 f4zero() { f32x4 v; v[0]=0.f; v[1]=0.f; v[2]=0.f; v[3]=0.f; return v; }

// write-through bf16 store: at coherence point once vmcnt retires.
DEVFN void gst_b16(__hip_bfloat16* p, __hip_bfloat16 v) {
  unsigned short u = __builtin_bit_cast(unsigned short, v);
  asm volatile("global_store_short %0, %1, off sc0 sc1" :: "v"(p), "v"(u));
}

// cache-bypassing 4B load/store (coherence-point access, fresh values)
DEVFN unsigned ld_cc(const unsigned* p) {
  unsigned v;
  asm volatile("global_load_dword %0, %1, off sc0 sc1\n\ts_waitcnt vmcnt(0)"
               : "=v"(v) : "v"(p) : "memory");
  return v;
}
DEVFN void st_cc(unsigned* p, unsigned v) {
  asm volatile("global_store_dword %0, %1, off sc0 sc1" :: "v"(p), "v"(v) : "memory");
}
DEVFN void ld3_cc(const unsigned* p0, const unsigned* p1, const unsigned* p2,
                  unsigned& a, unsigned& b, unsigned& c) {
  asm volatile("global_load_dword %0, %3, off sc0 sc1\n\t"
               "global_load_dword %1, %4, off sc0 sc1\n\t"
               "global_load_dword %2, %5, off sc0 sc1\n\t"
               "s_waitcnt vmcnt(0)"
               : "=&v"(a), "=&v"(b), "=&v"(c)
               : "v"(p0), "v"(p1), "v"(p2) : "memory");
}

DEVFN void fence_acq() { __builtin_amdgcn_fence(__ATOMIC_ACQUIRE, "agent"); }

// ---- sync word layout (unsigned, within 4096B):
//   [0..191]   init-barrier flags (one per block)
//   SFLAG(l,g) = 256 + (l*48+g)*4   gate-block "Sb(t) done" counters (value t+1)
//   PFLAG(l,p) = 832 + (l*16+p)*4   proj-block "h(t) done"  counters (value t+1)
#define SFLAG(s,l,g) ((s) + 256 + ((l)*48+(g))*4)
#define PFLAG(s,l,p) ((s) + 832 + ((l)*16+(p))*4)

// one-time full-grid barrier (packs done); decentralized: every block polls all 192.
DEVFN void init_barrier(unsigned* sync, int bid, int tid) {
  __syncthreads();                 // drains vmcnt: Xp pack stores at coherence point
  if (tid == 0) st_cc(sync + bid, 1u);
  if (tid < 64) {
    unsigned a, b, c;
    for (;;) {
      ld3_cc(sync + tid, sync + 64 + tid, sync + 128 + tid, a, b, c);
      if (__all((a >= 1u) & (b >= 1u) & (c >= 1u))) break;
      __builtin_amdgcn_s_sleep(1);
    }
    fence_acq();
  }
  __syncthreads();
}

// wait until nf flags (16B stride) all >= thr. Single LLC hop, no master.
DEVFN void wait_flags(const unsigned* base, int nf, int thr, int tid) {
  if (thr <= 0) return;            // data covered by an earlier fence (or memset)
  if (tid < 64) {
    const unsigned* p = base + tid * 4;
    for (;;) {
      int v = (tid < nf) ? (int)ld_cc(p) : 0x7fffffff;
      if (__all(v >= thr)) break;
      __builtin_amdgcn_s_sleep(1);
    }
    fence_acq();
  }
  __syncthreads();
}

// proj wait: own-layer gate flags >= thr1, plus (l<2) ring back-pressure
// sflag[l+1] >= thr2 (never blocks in steady state; guards Hr slot reuse).
DEVFN void wait_proj(const unsigned* sf_l, const unsigned* sf_lp1, int has2,
                     int thr1, int thr2, int tid) {
  if (tid < 64) {
    const unsigned* p1 = sf_l + tid * 4;
    const unsigned* p2 = sf_lp1 + tid * 4;
    for (;;) {
      int v1 = (tid < 48) ? (int)ld_cc(p1) : 0x7fffffff;
      int v2 = (has2 && tid < 48 && thr2 > 0) ? (int)ld_cc(p2) : 0x7fffffff;
      if (__all((v1 >= thr1) & (v2 >= thr2))) break;
      __builtin_amdgcn_s_sleep(1);
    }
    fence_acq();
  }
  __syncthreads();
}

// announce: data stores drained (syncthreads => vmcnt(0)), then flag store.
DEVFN void set_flag(unsigned* p, unsigned v, int tid) {
  __syncthreads();
  if (tid == 0) st_cc(p, v);
}

__global__ __launch_bounds__(NTHR, 1)
void lstmp_persistent(const float* __restrict__ xin,
                      const float* __restrict__ W0, const float* __restrict__ b0, const float* __restrict__ Wp0,
                      const float* __restrict__ W1, const float* __restrict__ b1, const float* __restrict__ Wp1,
                      const float* __restrict__ W2, const float* __restrict__ b2, const float* __restrict__ Wp2,
                      float* __restrict__ outp, unsigned char* __restrict__ ws)
{
  __shared__ __align__(16) __hip_bfloat16 lds[LDS_ELEMS];

  const int bid  = blockIdx.x;
  const int tid  = threadIdx.x;
  const int lane = tid & 63;
  const int wave = tid >> 6;
  const int q    = lane >> 4;     // 0..3
  const int c16  = lane & 15;

  __hip_bfloat16* Xp = (__hip_bfloat16*)(ws + XP_OFF);  // [160][640][64] bf16, cols>=40 zero
  __hip_bfloat16* Hr = (__hip_bfloat16*)(ws + HR_OFF);  // [3][4 ring][640][256] bf16; slot (t+1)&3 holds h(t)
  __hip_bfloat16* Sb = (__hip_bfloat16*)(ws + SB_OFF);  // [3][640][768] bf16
  unsigned* sync     = (unsigned*)(ws + SYNC_OFF);

  // ---- XCD-aware role decode: bid%8 == XCD (round-robin dispatch, 24 blocks/XCD).
  const int xcd  = bid & 7;
  const int slot = bid >> 3;      // 0..23
  const bool isGate = (xcd < 6);
  int l = 0, bc = 0, hg = 0, mt = 0, nt = 0;
  if (isGate) { l = xcd >> 1; bc = xcd & 1; hg = slot; }
  else        { l = slot >> 3; int r = slot & 7; mt = (xcd - 6) * 2 + (r >> 2); nt = r & 3; }

  const int KX  = (l == 0) ? KX0 : 256;
  const int KT  = KX + KH;                  // 320 or 512
  const int STW = (l == 0) ? STW1 : STW2;

  const float* Wl  = (l == 0) ? W0  : ((l == 1) ? W1  : W2);
  const float* bl  = (l == 0) ? b0  : ((l == 1) ? b1  : b2);
  const float* Wpl = (l == 0) ? Wp0 : ((l == 1) ? Wp1 : Wp2);

  // ---------- pre-phase: pack x -> Xp (all blocks share the work) ----------
  for (int e = bid * NTHR + tid; e < TT * BB * 64; e += NWG * NTHR) {
    int k  = e & 63;
    int tb = e >> 6;
    float v = (k < DD) ? xin[(size_t)tb * DD + k] : 0.f;
    gst_b16(&Xp[e], __float2bfloat16(v));
  }

  // ---------- pre-phase: pack weights (transposed) into this block's LDS ----------
  if (isGate) {
    for (int idx = tid; idx < 128 * KT; idx += NTHR) {
      int kk = idx >> 7;
      int nn = idx & 127;
      int col = (nn >> 5) * HH + hg * 32 + (nn & 31);
      float v;
      if (l == 0) {
        v = (kk < DD) ? Wl[(size_t)kk * G4H + col]
                      : ((kk < KX0) ? 0.f : Wl[(size_t)(kk - 24) * G4H + col]);
      } else {
        v = Wl[(size_t)kk * G4H + col];
      }
      lds[nn * STW + kk] = __float2bfloat16(v);
    }
  } else {
    for (int idx = tid; idx < 64 * HH; idx += NTHR) {
      int kk = idx >> 6;
      int nn = idx & 63;
      lds[nn * STP + kk] = __float2bfloat16(Wpl[(size_t)kk * PP + nt * 64 + nn]);
    }
  }

  init_barrier(sync, bid, tid);     // packs done (Xp + LDS weights)

  if (isGate) {
    // ----- GATE PATH -----
    const int gid = bc * 24 + hg;
    unsigned* myflag = SFLAG(sync, l, gid);
    const unsigned* pf_own = PFLAG(sync, l, 0);
    const unsigned* pf_prv = (l > 0) ? PFLAG(sync, l - 1, 0) : PFLAG(sync, l, 0);

    const int wmg = wave >> 1, wng = wave & 1;
    const int m0g = bc * 320 + wmg * 160;
    const int hcl = wng * 16 + c16;
    float biasv[4];
#pragma unroll
    for (int g = 0; g < 4; ++g) biasv[g] = bl[g * HH + hg * 32 + hcl];

    f32x4 acc[10][4];
    float cst[10][4];
#pragma unroll
    for (int mi = 0; mi < 10; ++mi)
#pragma unroll
      for (int g = 0; g < 4; ++g) { acc[mi][g] = f4zero(); cst[mi][g] = 0.f; }

    auto gate_gemm = [&](const __hip_bfloat16* A, int lda, int kbase, int klen) {
      for (int ks = 0; ks < klen; ks += 32) {
        s16x8 av[10];
#pragma unroll
        for (int mi = 0; mi < 10; ++mi)
          av[mi] = *(const s16x8*)(A + (size_t)(m0g + mi * 16 + c16) * lda + ks + 8 * q);
        s16x8 bv[4];
#pragma unroll
        for (int g = 0; g < 4; ++g)
          bv[g] = *(const s16x8*)(lds + (g * 32 + hcl) * STW + kbase + ks + 8 * q);
#pragma unroll
        for (int mi = 0; mi < 10; ++mi)
#pragma unroll
          for (int g = 0; g < 4; ++g)
            acc[mi][g] = __builtin_amdgcn_mfma_f32_16x16x32_bf16(av[mi], bv[g], acc[mi][g], 0, 0, 0);
      }
    };

    auto gate_update = [&]() {
      __hip_bfloat16* S = Sb + (size_t)l * BB * HH;
#pragma unroll
      for (int mi = 0; mi < 10; ++mi) {
#pragma unroll
        for (int r = 0; r < 4; ++r) {
          float iv = acc[mi][0][r] + biasv[0];
          float jv = acc[mi][1][r] + biasv[1];
          float fv = acc[mi][2][r] + biasv[2];
          float ov = acc[mi][3][r] + biasv[3];
          float c  = sigm(fv + 1.f) * cst[mi][r] + sigm(iv) * tanh_(jv);
          cst[mi][r] = c;
          float sv = sigm(ov) * tanh_(c);
          gst_b16(&S[(size_t)(m0g + mi * 16 + q * 4 + r) * HH + hg * 32 + hcl],
                  __float2bfloat16(sv));
        }
#pragma unroll
        for (int g = 0; g < 4; ++g) acc[mi][g] = f4zero();
      }
    };

    // zx(0): layer0 from Xp; l>0 from h_{l-1}(0) once proj(l-1) flags t'=0 done.
    if (l == 0) gate_gemm(Xp, 64, 0, KX0);
    else {
      wait_flags(pf_prv, 16, 1, tid);
      gate_gemm(Hr + ((size_t)(l - 1) * 4 + 1) * BB * PP, PP, 0, 256);
    }

    for (int t = 0; t < TT; ++t) {
      // h_l(t-1) ready when proj l has completed t-1 timesteps (flag >= t)
      wait_flags(pf_own, 16, t, tid);
      gate_gemm(Hr + ((size_t)l * 4 + ((unsigned)t & 3)) * BB * PP, PP, KX, KH);
      gate_update();
      set_flag(myflag, (unsigned)(t + 1), tid);
      // x-shadow zx(t+1): runs in proj's shadow, off the waiting path
      if (t + 1 < TT) {
        if (l == 0) gate_gemm(Xp + (size_t)(t + 1) * BB * 64, 64, 0, KX0);
        else {
          wait_flags(pf_prv, 16, t + 2, tid);   // h_{l-1}(t+1) ready
          gate_gemm(Hr + ((size_t)(l - 1) * 4 + ((unsigned)(t + 2) & 3)) * BB * PP, PP, 0, 256);
        }
      }
    }
  } else {
    // ----- PROJ PATH: lean registers, 2-deep ping-pong K-loop -----
    const int pid = mt * 4 + nt;
    unsigned* myflag = PFLAG(sync, l, pid);
    const unsigned* sf_own = SFLAG(sync, l, 0);
    const unsigned* sf_nxt = (l < 2) ? SFLAG(sync, l + 1, 0) : SFLAG(sync, l, 0);
    const int m0p = mt * 160 + (wave >> 1) * 80;
    const int np0 = (wave & 1) * 32;

    for (int t = 0; t < TT; ++t) {
      // Sb_l(t) ready (48 gate flags >= t+1); ring back-pressure vs layer l+1.
      wait_proj(sf_own, sf_nxt, l < 2 ? 1 : 0, t + 1, t - 3, tid);

      const __hip_bfloat16* A = Sb + (size_t)l * BB * HH;
      const __hip_bfloat16* ab[5];
#pragma unroll
      for (int mi = 0; mi < 5; ++mi)
        ab[mi] = A + (size_t)(m0p + mi * 16 + c16) * HH + 8 * q;

      f32x4 pa[5][2];
#pragma unroll
      for (int mi = 0; mi < 5; ++mi) { pa[mi][0] = f4zero(); pa[mi][1] = f4zero(); }

      s16x8 a0[5], a1[5];                   // ping-pong prefetch
#pragma unroll
      for (int mi = 0; mi < 5; ++mi) a0[mi] = *(const s16x8*)(ab[mi] + 0);

#pragma unroll 1
      for (int it2 = 0; it2 < 12; ++it2) {  // 2 k-slices per iteration
        const int ks0 = it2 * 64, ks1 = ks0 + 32;
#pragma unroll
        for (int mi = 0; mi < 5; ++mi) a1[mi] = *(const s16x8*)(ab[mi] + ks1);
        s16x8 bv[2];
#pragma unroll
        for (int ni = 0; ni < 2; ++ni)
          bv[ni] = *(const s16x8*)(lds + (np0 + ni * 16 + c16) * STP + ks0 + 8 * q);
#pragma unroll
        for (int mi = 0; mi < 5; ++mi)
#pragma unroll
          for (int ni = 0; ni < 2; ++ni)
            pa[mi][ni] = __builtin_amdgcn_mfma_f32_16x16x32_bf16(a0[mi], bv[ni], pa[mi][ni], 0, 0, 0);
        if (it2 < 11) {
#pragma unroll
          for (int mi = 0; mi < 5; ++mi) a0[mi] = *(const s16x8*)(ab[mi] + ks0 + 64);
        }
#pragma unroll
        for (int ni = 0; ni < 2; ++ni)
          bv[ni] = *(const s16x8*)(lds + (np0 + ni * 16 + c16) * STP + ks1 + 8 * q);
#pragma unroll
        for (int mi = 0; mi < 5; ++mi)
#pragma unroll
          for (int ni = 0; ni < 2; ++ni)
            pa[mi][ni] = __builtin_amdgcn_mfma_f32_16x16x32_bf16(a1[mi], bv[ni], pa[mi][ni], 0, 0, 0);
      }

      __hip_bfloat16* Hd = Hr + ((size_t)l * 4 + ((unsigned)(t + 1) & 3)) * BB * PP;
#pragma unroll
      for (int mi = 0; mi < 5; ++mi)
#pragma unroll
        for (int ni = 0; ni < 2; ++ni)
#pragma unroll
          for (int r = 0; r < 4; ++r)
            gst_b16(&Hd[(size_t)(m0p + mi * 16 + q * 4 + r) * PP + nt * 64 + np0 + ni * 16 + c16],
                    __float2bfloat16(pa[mi][ni][r]));

      set_flag(myflag, (unsigned)(t + 1), tid);
    }
  }

  // ---------- epilogue: L2-normalize h_2(159) (ring slot (159+1)&3 = 0) ----------
  wait_flags(PFLAG(sync, 2, 0), 16, TT, tid);
  const __hip_bfloat16* hf = Hr + (size_t)(2 * 4 + 0) * BB * PP;
  float* red = reinterpret_cast<float*>(lds);   // weights dead now, reuse LDS
  for (int row = bid; row < BB; row += NWG) {
    float v = __bfloat162float(hf[(size_t)row * PP + tid]);
    float ssq = v * v;
#pragma unroll
    for (int off = 32; off > 0; off >>= 1) ssq += __shfl_down(ssq, off, 64);
    if (lane == 0) red[wave] = ssq;
    __syncthreads();
    float tot = red[0] + red[1] + red[2] + red[3];
    outp[(size_t)row * PP + tid] = v * __fdividef(1.f, sqrtf(tot) + 1e-6f);
    __syncthreads();
  }
}

extern "C" void kernel_launch(void* const* d_in, const int* in_sizes, int n_in,
                              void* d_out, int out_size, void* d_ws, size_t ws_size,
                              hipStream_t stream) {
  (void)in_sizes; (void)n_in; (void)out_size; (void)ws_size;
  unsigned char* ws = (unsigned char*)d_ws;
  // zero h-ring (h_{-1} = 0) and all sync flags every call (replay-safe)
  hipMemsetAsync(ws + HR_OFF, 0, HR_BYTES, stream);
  hipMemsetAsync(ws + SYNC_OFF, 0, SYNC_BYTES, stream);
  lstmp_persistent<<<dim3(NWG), dim3(NTHR), 0, stream>>>(
      (const float*)d_in[0],
      (const float*)d_in[1], (const float*)d_in[2], (const float*)d_in[3],
      (const float*)d_in[4], (const float*)d_in[5], (const float*)d_in[6],
      (const float*)d_in[7], (const float*)d_in[8], (const float*)d_in[9],
      (float*)d_out, ws);
}

// Round 8
// 5607.908 us; speedup vs baseline: 1.4913x; 1.1049x over previous
//
#include <hip/hip_runtime.h>
#include <hip/hip_bf16.h>

typedef __attribute__((ext_vector_type(4))) float f32x4;
typedef __attribute__((ext_vector_type(8))) short s16x8;

#define DEVFN static __device__ __forceinline__

// ---- problem sizes ----
#define TT  160
#define BB  640
#define DD  40
#define HH  768
#define PP  256
#define G4H 3072

// ---- geometry ----
#define NWG   192
#define NTHR  256

#define KH  256
#define KX0 64         // layer0 x-K padded 40 -> 64

// LDS strides (elements), +8 pad keeps 16B alignment and breaks worst conflicts
#define STW1 328       // layer0: 320+8
#define STW2 520       // layer1/2: 512+8
#define STP  776       // proj: 768+8
#define LDS_ELEMS 66560  // 128*520 = 133,120 bytes

// ---- workspace layout ----
#define XP_BYTES   (TT*BB*64*2)
#define HR_BYTES   (3*4*BB*PP*2)
#define SB_BYTES   (3*BB*HH*2)
#define XP_OFF     0
#define HR_OFF     (XP_OFF + XP_BYTES)
#define SB_OFF     (HR_OFF + HR_BYTES)
#define SYNC_OFF   (SB_OFF + SB_BYTES)
#define SYNC_BYTES 4096

DEVFN float sigm(float v)  { return __fdividef(1.f, 1.f + __expf(-v)); }
DEVFN float tanh_(float v) { return 2.f * __fdividef(1.f, 1.f + __expf(-2.f * v)) - 1.f; }
DEVFN f32x4 f4zero() { f32x4 v; v[0]=0.f; v[1]=0.f; v[2]=0.f; v[3]=0.f; return v; }

// write-through bf16 store: at coherence point once vmcnt retires.
DEVFN void gst_b16(__hip_bfloat16* p, __hip_bfloat16 v) {
  unsigned short u = __builtin_bit_cast(unsigned short, v);
  asm volatile("global_store_short %0, %1, off sc0 sc1" :: "v"(p), "v"(u));
}

// cache-bypassing 4B load/store (coherence-point access, fresh values)
DEVFN unsigned ld_cc(const unsigned* p) {
  unsigned v;
  asm volatile("global_load_dword %0, %1, off sc0 sc1\n\ts_waitcnt vmcnt(0)"
               : "=v"(v) : "v"(p) : "memory");
  return v;
}
DEVFN void st_cc(unsigned* p, unsigned v) {
  asm volatile("global_store_dword %0, %1, off sc0 sc1" :: "v"(p), "v"(v) : "memory");
}
DEVFN void ld3_cc(const unsigned* p0, const unsigned* p1, const unsigned* p2,
                  unsigned& a, unsigned& b, unsigned& c) {
  asm volatile("global_load_dword %0, %3, off sc0 sc1\n\t"
               "global_load_dword %1, %4, off sc0 sc1\n\t"
               "global_load_dword %2, %5, off sc0 sc1\n\t"
               "s_waitcnt vmcnt(0)"
               : "=&v"(a), "=&v"(b), "=&v"(c)
               : "v"(p0), "v"(p1), "v"(p2) : "memory");
}

DEVFN void fence_acq() { __builtin_amdgcn_fence(__ATOMIC_ACQUIRE, "agent"); }

// ---- sync word layout (unsigned, within 4096B):
//   [0..191]   init-barrier flags (one per block)
//   SFLAG(l,g) = 256 + (l*48+g)*4   gate-block "Sb(t) done" counters (value t+1)
//   PFLAG(l,p) = 832 + (l*16+p)*4   proj-block "h(t) done"  counters (value t+1)
#define SFLAG(s,l,g) ((s) + 256 + ((l)*48+(g))*4)
#define PFLAG(s,l,p) ((s) + 832 + ((l)*16+(p))*4)

// one-time full-grid barrier (packs done); decentralized: every block polls all 192.
// BUSY SPIN (no s_sleep): keeps CU power state up, fastest detect.
DEVFN void init_barrier(unsigned* sync, int bid, int tid) {
  __syncthreads();                 // drains vmcnt: Xp pack stores at coherence point
  if (tid == 0) st_cc(sync + bid, 1u);
  if (tid < 64) {
    unsigned a, b, c;
    for (;;) {
      ld3_cc(sync + tid, sync + 64 + tid, sync + 128 + tid, a, b, c);
      if (__all((a >= 1u) & (b >= 1u) & (c >= 1u))) break;
    }
    fence_acq();
  }
  __syncthreads();
}

// wait until nf flags (16B stride) all >= thr. Single LLC hop, busy spin.
DEVFN void wait_flags(const unsigned* base, int nf, int thr, int tid) {
  if (thr <= 0) return;            // data covered by an earlier fence (or memset)
  if (tid < 64) {
    const unsigned* p = base + tid * 4;
    for (;;) {
      int v = (tid < nf) ? (int)ld_cc(p) : 0x7fffffff;
      if (__all(v >= thr)) break;
    }
    fence_acq();
  }
  __syncthreads();
}

// proj wait: own-layer gate flags >= thr1, plus (l<2) ring back-pressure
// sflag[l+1] >= thr2 (never blocks in steady state; guards Hr slot reuse).
DEVFN void wait_proj(const unsigned* sf_l, const unsigned* sf_lp1, int has2,
                     int thr1, int thr2, int tid) {
  if (tid < 64) {
    const unsigned* p1 = sf_l + tid * 4;
    const unsigned* p2 = sf_lp1 + tid * 4;
    for (;;) {
      int v1 = (tid < 48) ? (int)ld_cc(p1) : 0x7fffffff;
      int v2 = (has2 && tid < 48 && thr2 > 0) ? (int)ld_cc(p2) : 0x7fffffff;
      if (__all((v1 >= thr1) & (v2 >= thr2))) break;
    }
    fence_acq();
  }
  __syncthreads();
}

// announce: data stores drained (syncthreads => vmcnt(0)), then flag store.
DEVFN void set_flag(unsigned* p, unsigned v, int tid) {
  __syncthreads();
  if (tid == 0) st_cc(p, v);
}

__global__ __launch_bounds__(NTHR, 1)
void lstmp_persistent(const float* __restrict__ xin,
                      const float* __restrict__ W0, const float* __restrict__ b0, const float* __restrict__ Wp0,
                      const float* __restrict__ W1, const float* __restrict__ b1, const float* __restrict__ Wp1,
                      const float* __restrict__ W2, const float* __restrict__ b2, const float* __restrict__ Wp2,
                      float* __restrict__ outp, unsigned char* __restrict__ ws)
{
  __shared__ __align__(16) __hip_bfloat16 lds[LDS_ELEMS];

  const int bid  = blockIdx.x;
  const int tid  = threadIdx.x;
  const int lane = tid & 63;
  const int wave = tid >> 6;
  const int q    = lane >> 4;     // 0..3
  const int c16  = lane & 15;

  __hip_bfloat16* Xp = (__hip_bfloat16*)(ws + XP_OFF);  // [160][640][64] bf16, cols>=40 zero
  __hip_bfloat16* Hr = (__hip_bfloat16*)(ws + HR_OFF);  // [3][4 ring][640][256] bf16; slot (t+1)&3 holds h(t)
  __hip_bfloat16* Sb = (__hip_bfloat16*)(ws + SB_OFF);  // [3][640][768] bf16
  unsigned* sync     = (unsigned*)(ws + SYNC_OFF);

  // ---- XCD-aware role decode: bid%8 == XCD (round-robin dispatch, 24 blocks/XCD).
  const int xcd  = bid & 7;
  const int slot = bid >> 3;      // 0..23
  const bool isGate = (xcd < 6);
  int l = 0, bc = 0, hg = 0, mt = 0, nt = 0;
  if (isGate) { l = xcd >> 1; bc = xcd & 1; hg = slot; }
  else        { l = slot >> 3; int r = slot & 7; mt = (xcd - 6) * 2 + (r >> 2); nt = r & 3; }

  const int KX  = (l == 0) ? KX0 : 256;
  const int KT  = KX + KH;                  // 320 or 512
  const int STW = (l == 0) ? STW1 : STW2;

  const float* Wl  = (l == 0) ? W0  : ((l == 1) ? W1  : W2);
  const float* bl  = (l == 0) ? b0  : ((l == 1) ? b1  : b2);
  const float* Wpl = (l == 0) ? Wp0 : ((l == 1) ? Wp1 : Wp2);

  // ---------- pre-phase: pack x -> Xp (all blocks share the work) ----------
  for (int e = bid * NTHR + tid; e < TT * BB * 64; e += NWG * NTHR) {
    int k  = e & 63;
    int tb = e >> 6;
    float v = (k < DD) ? xin[(size_t)tb * DD + k] : 0.f;
    gst_b16(&Xp[e], __float2bfloat16(v));
  }

  // ---------- pre-phase: pack weights (transposed) into this block's LDS ----------
  if (isGate) {
    for (int idx = tid; idx < 128 * KT; idx += NTHR) {
      int kk = idx >> 7;
      int nn = idx & 127;
      int col = (nn >> 5) * HH + hg * 32 + (nn & 31);
      float v;
      if (l == 0) {
        v = (kk < DD) ? Wl[(size_t)kk * G4H + col]
                      : ((kk < KX0) ? 0.f : Wl[(size_t)(kk - 24) * G4H + col]);
      } else {
        v = Wl[(size_t)kk * G4H + col];
      }
      lds[nn * STW + kk] = __float2bfloat16(v);
    }
  } else {
    for (int idx = tid; idx < 64 * HH; idx += NTHR) {
      int kk = idx >> 6;
      int nn = idx & 63;
      lds[nn * STP + kk] = __float2bfloat16(Wpl[(size_t)kk * PP + nt * 64 + nn]);
    }
  }

  init_barrier(sync, bid, tid);     // packs done (Xp + LDS weights)

  if (isGate) {
    // ----- GATE PATH -----
    const int gid = bc * 24 + hg;
    unsigned* myflag = SFLAG(sync, l, gid);
    const unsigned* pf_own = PFLAG(sync, l, 0);
    const unsigned* pf_prv = (l > 0) ? PFLAG(sync, l - 1, 0) : PFLAG(sync, l, 0);

    const int wmg = wave >> 1, wng = wave & 1;
    const int m0g = bc * 320 + wmg * 160;
    const int hcl = wng * 16 + c16;
    float biasv[4];
#pragma unroll
    for (int g = 0; g < 4; ++g) biasv[g] = bl[g * HH + hg * 32 + hcl];

    f32x4 acc[10][4];
    float cst[10][4];
#pragma unroll
    for (int mi = 0; mi < 10; ++mi)
#pragma unroll
      for (int g = 0; g < 4; ++g) { acc[mi][g] = f4zero(); cst[mi][g] = 0.f; }

    // 5/5 m-split ping-pong: group-B loads overlap group-A MFMAs and vice
    // versa. NOTE: A's K-offset is ks ONLY (A always starts at k=0);
    // kbase applies to the LDS B-tile rows exclusively (round-7 bug fix).
    auto gate_gemm = [&](const __hip_bfloat16* A, int lda, int kbase, int klen) {
      s16x8 avA[5], avB[5];
#pragma unroll
      for (int mi = 0; mi < 5; ++mi)
        avA[mi] = *(const s16x8*)(A + (size_t)(m0g + mi * 16 + c16) * lda + 8 * q);
#pragma unroll 1
      for (int ks = 0; ks < klen; ks += 32) {
#pragma unroll
        for (int mi = 0; mi < 5; ++mi)
          avB[mi] = *(const s16x8*)(A + (size_t)(m0g + (5 + mi) * 16 + c16) * lda + ks + 8 * q);
        s16x8 bv[4];
#pragma unroll
        for (int g = 0; g < 4; ++g)
          bv[g] = *(const s16x8*)(lds + (g * 32 + hcl) * STW + kbase + ks + 8 * q);
#pragma unroll
        for (int mi = 0; mi < 5; ++mi)
#pragma unroll
          for (int g = 0; g < 4; ++g)
            acc[mi][g] = __builtin_amdgcn_mfma_f32_16x16x32_bf16(avA[mi], bv[g], acc[mi][g], 0, 0, 0);
        if (ks + 32 < klen) {
#pragma unroll
          for (int mi = 0; mi < 5; ++mi)
            avA[mi] = *(const s16x8*)(A + (size_t)(m0g + mi * 16 + c16) * lda + ks + 32 + 8 * q);
        }
#pragma unroll
        for (int mi = 0; mi < 5; ++mi)
#pragma unroll
          for (int g = 0; g < 4; ++g)
            acc[5 + mi][g] = __builtin_amdgcn_mfma_f32_16x16x32_bf16(avB[mi], bv[g], acc[5 + mi][g], 0, 0, 0);
      }
    };

    auto gate_update = [&]() {
      __hip_bfloat16* S = Sb + (size_t)l * BB * HH;
#pragma unroll
      for (int mi = 0; mi < 10; ++mi) {
#pragma unroll
        for (int r = 0; r < 4; ++r) {
          float iv = acc[mi][0][r] + biasv[0];
          float jv = acc[mi][1][r] + biasv[1];
          float fv = acc[mi][2][r] + biasv[2];
          float ov = acc[mi][3][r] + biasv[3];
          float c  = sigm(fv + 1.f) * cst[mi][r] + sigm(iv) * tanh_(jv);
          cst[mi][r] = c;
          float sv = sigm(ov) * tanh_(c);
          gst_b16(&S[(size_t)(m0g + mi * 16 + q * 4 + r) * HH + hg * 32 + hcl],
                  __float2bfloat16(sv));
        }
#pragma unroll
        for (int g = 0; g < 4; ++g) acc[mi][g] = f4zero();
      }
    };

    // zx(0): layer0 from Xp; l>0 from h_{l-1}(0) once proj(l-1) flags t'=0 done.
    if (l == 0) gate_gemm(Xp, 64, 0, KX0);
    else {
      wait_flags(pf_prv, 16, 1, tid);
      gate_gemm(Hr + ((size_t)(l - 1) * 4 + 1) * BB * PP, PP, 0, 256);
    }

    for (int t = 0; t < TT; ++t) {
      // h_l(t-1) ready when proj l has completed t-1 timesteps (flag >= t)
      wait_flags(pf_own, 16, t, tid);
      gate_gemm(Hr + ((size_t)l * 4 + ((unsigned)t & 3)) * BB * PP, PP, KX, KH);
      gate_update();
      set_flag(myflag, (unsigned)(t + 1), tid);
      // x-shadow zx(t+1): runs in proj's shadow, off the waiting path
      if (t + 1 < TT) {
        if (l == 0) gate_gemm(Xp + (size_t)(t + 1) * BB * 64, 64, 0, KX0);
        else {
          wait_flags(pf_prv, 16, t + 2, tid);   // h_{l-1}(t+1) ready
          gate_gemm(Hr + ((size_t)(l - 1) * 4 + ((unsigned)(t + 2) & 3)) * BB * PP, PP, 0, 256);
        }
      }
    }
  } else {
    // ----- PROJ PATH: lean registers, 2-deep ping-pong K-loop -----
    const int pid = mt * 4 + nt;
    unsigned* myflag = PFLAG(sync, l, pid);
    const unsigned* sf_own = SFLAG(sync, l, 0);
    const unsigned* sf_nxt = (l < 2) ? SFLAG(sync, l + 1, 0) : SFLAG(sync, l, 0);
    const int m0p = mt * 160 + (wave >> 1) * 80;
    const int np0 = (wave & 1) * 32;

    for (int t = 0; t < TT; ++t) {
      // Sb_l(t) ready (48 gate flags >= t+1); ring back-pressure vs layer l+1.
      wait_proj(sf_own, sf_nxt, l < 2 ? 1 : 0, t + 1, t - 3, tid);

      const __hip_bfloat16* A = Sb + (size_t)l * BB * HH;
      const __hip_bfloat16* ab[5];
#pragma unroll
      for (int mi = 0; mi < 5; ++mi)
        ab[mi] = A + (size_t)(m0p + mi * 16 + c16) * HH + 8 * q;

      f32x4 pa[5][2];
#pragma unroll
      for (int mi = 0; mi < 5; ++mi) { pa[mi][0] = f4zero(); pa[mi][1] = f4zero(); }

      s16x8 a0[5], a1[5];                   // ping-pong prefetch
#pragma unroll
      for (int mi = 0; mi < 5; ++mi) a0[mi] = *(const s16x8*)(ab[mi] + 0);

#pragma unroll 1
      for (int it2 = 0; it2 < 12; ++it2) {  // 2 k-slices per iteration
        const int ks0 = it2 * 64, ks1 = ks0 + 32;
#pragma unroll
        for (int mi = 0; mi < 5; ++mi) a1[mi] = *(const s16x8*)(ab[mi] + ks1);
        s16x8 bv[2];
#pragma unroll
        for (int ni = 0; ni < 2; ++ni)
          bv[ni] = *(const s16x8*)(lds + (np0 + ni * 16 + c16) * STP + ks0 + 8 * q);
#pragma unroll
        for (int mi = 0; mi < 5; ++mi)
#pragma unroll
          for (int ni = 0; ni < 2; ++ni)
            pa[mi][ni] = __builtin_amdgcn_mfma_f32_16x16x32_bf16(a0[mi], bv[ni], pa[mi][ni], 0, 0, 0);
        if (it2 < 11) {
#pragma unroll
          for (int mi = 0; mi < 5; ++mi) a0[mi] = *(const s16x8*)(ab[mi] + ks0 + 64);
        }
#pragma unroll
        for (int ni = 0; ni < 2; ++ni)
          bv[ni] = *(const s16x8*)(lds + (np0 + ni * 16 + c16) * STP + ks1 + 8 * q);
#pragma unroll
        for (int mi = 0; mi < 5; ++mi)
#pragma unroll
          for (int ni = 0; ni < 2; ++ni)
            pa[mi][ni] = __builtin_amdgcn_mfma_f32_16x16x32_bf16(a1[mi], bv[ni], pa[mi][ni], 0, 0, 0);
      }

      __hip_bfloat16* Hd = Hr + ((size_t)l * 4 + ((unsigned)(t + 1) & 3)) * BB * PP;
#pragma unroll
      for (int mi = 0; mi < 5; ++mi)
#pragma unroll
        for (int ni = 0; ni < 2; ++ni)
#pragma unroll
          for (int r = 0; r < 4; ++r)
            gst_b16(&Hd[(size_t)(m0p + mi * 16 + q * 4 + r) * PP + nt * 64 + np0 + ni * 16 + c16],
                    __float2bfloat16(pa[mi][ni][r]));

      set_flag(myflag, (unsigned)(t + 1), tid);
    }
  }

  // ---------- epilogue: L2-normalize h_2(159) (ring slot (159+1)&3 = 0) ----------
  wait_flags(PFLAG(sync, 2, 0), 16, TT, tid);
  const __hip_bfloat16* hf = Hr + (size_t)(2 * 4 + 0) * BB * PP;
  float* red = reinterpret_cast<float*>(lds);   // weights dead now, reuse LDS
  for (int row = bid; row < BB; row += NWG) {
    float v = __bfloat162float(hf[(size_t)row * PP + tid]);
    float ssq = v * v;
#pragma unroll
    for (int off = 32; off > 0; off >>= 1) ssq += __shfl_down(ssq, off, 64);
    if (lane == 0) red[wave] = ssq;
    __syncthreads();
    float tot = red[0] + red[1] + red[2] + red[3];
    outp[(size_t)row * PP + tid] = v * __fdividef(1.f, sqrtf(tot) + 1e-6f);
    __syncthreads();
  }
}

extern "C" void kernel_launch(void* const* d_in, const int* in_sizes, int n_in,
                              void* d_out, int out_size, void* d_ws, size_t ws_size,
                              hipStream_t stream) {
  (void)in_sizes; (void)n_in; (void)out_size; (void)ws_size;
  unsigned char* ws = (unsigned char*)d_ws;
  // zero h-ring (h_{-1} = 0) and all sync flags every call (replay-safe)
  hipMemsetAsync(ws + HR_OFF, 0, HR_BYTES, stream);
  hipMemsetAsync(ws + SYNC_OFF, 0, SYNC_BYTES, stream);
  lstmp_persistent<<<dim3(NWG), dim3(NTHR), 0, stream>>>(
      (const float*)d_in[0],
      (const float*)d_in[1], (const float*)d_in[2], (const float*)d_in[3],
      (const float*)d_in[4], (const float*)d_in[5], (const float*)d_in[6],
      (const float*)d_in[7], (const float*)d_in[8], (const float*)d_in[9],
      (float*)d_out, ws);
}